// Round 4
// baseline (1103.611 us; speedup 1.0000x reference)
//
#include <hip/hip_runtime.h>
#include <hip/hip_bf16.h>

#define NPART 22
#define NDEG  21
#define NEDGE 462
#define HID   64
#define NLAYERS 4
#define NSTRIP 29
#define NS    68     // padded row stride (floats) for node-indexed arrays
#define MWS   68     // u32 row stride of wave-private m tile

typedef __attribute__((ext_vector_type(8))) short bf16x8;
typedef __attribute__((ext_vector_type(4))) float f32x4;
typedef __attribute__((ext_vector_type(4))) unsigned int u32x4;

__device__ __forceinline__ float silu_f(float v) {
    return __fdividef(v, 1.0f + __expf(-v));
}
__device__ __forceinline__ unsigned short bfu(float v) {
    return __bfloat16_as_ushort(__float2bfloat16(v));
}
__device__ __forceinline__ float bf2f(unsigned h) { return __uint_as_float(h << 16); }

// pack f32 -> (hi bf16) | (lo bf16 << 16)
__device__ __forceinline__ unsigned pack_hl(float v) {
    unsigned short h = bfu(v);
    float r = v - bf2f(h);
    return (unsigned)h | ((unsigned)bfu(r) << 16);
}

// split 8 f32 into hi/lo bf16x8 fragments
__device__ __forceinline__ void split8(const float* va, bf16x8& hi, bf16x8& lo) {
    #pragma unroll
    for (int i = 0; i < 8; ++i) {
        unsigned short h = bfu(va[i]);
        hi[i] = (short)h;
        lo[i] = (short)bfu(va[i] - bf2f(h));
    }
}

// Stage 64x64 f32 row-major [k][j] -> LDS transposed single bf16 [j][k],
// row 128 B, swizzle: byte_k ^ ((j&7)<<4).  512 threads.
__device__ __forceinline__ void stage_wt(const float* __restrict__ Wg,
                                         char* dst, int tid) {
    const int j  = tid & 63;
    const int kb = tid >> 6;     // 0..7 -> 8 k each
    u32x4 p;
    #pragma unroll
    for (int i = 0; i < 8; i += 2) {
        float v0 = Wg[(kb*8 + i) * 64 + j];
        float v1 = Wg[(kb*8 + i + 1) * 64 + j];
        p[i >> 1] = (unsigned)bfu(v0) | ((unsigned)bfu(v1) << 16);
    }
    *(u32x4*)(dst + j * 128 + ((kb*16) ^ ((j & 7) << 4))) = p;
}

__global__ __launch_bounds__(512, 4)
void egnn_fused(const float* __restrict__ t_in,
                const float* __restrict__ xs,
                const float* __restrict__ h_init,
                const float* __restrict__ emb_w,
                const float* __restrict__ emb_b,
                const float* __restrict__ edge_w1,
                const float* __restrict__ edge_b1,
                const float* __restrict__ edge_w2,
                const float* __restrict__ edge_b2,
                const float* __restrict__ node_w1,
                const float* __restrict__ node_b1,
                const float* __restrict__ node_w2,
                const float* __restrict__ node_b2,
                const float* __restrict__ coord_w1,
                const float* __restrict__ coord_b1,
                const float* __restrict__ coord_w2,
                float* __restrict__ out)
{
    __shared__ __align__(16) char     wbuf[16384];          // W2t bf16 | Wc1t bf16
    __shared__ __align__(16) unsigned mwav[8 * 16 * MWS];   // packed hi/lo m tiles
    __shared__ __align__(16) float hsh [NPART][NS];
    __shared__ __align__(16) float Hr  [NPART][NS];         // also hn scratch
    __shared__ __align__(16) float Hc  [NPART][NS];
    __shared__ __align__(16) float aggs[NPART][NS];
    __shared__ float vrad[HID], vea[HID], vb2[HID];
    __shared__ float vcb1[HID], vcw2[HID], vbn1[HID], vbn2[HID];
    __shared__ float xl[NPART][3], x0l[NPART][3], dxl[NPART][3];
    __shared__ float scal_sw[8][16];
    __shared__ unsigned char srcT[464], dstT[464];
    __shared__ float meanv[3];

    const int b   = blockIdx.x;
    const int tid = threadIdx.x;
    const int l   = tid & 63;
    const int w   = tid >> 6;          // 0..7
    const int kg  = l >> 4;
    const int j0  = l & 15;
    const float tb = t_in[b];
    float* aggsF = &aggs[0][0];
    unsigned* mw = mwav + w * 16 * MWS;

    // ---- init ----
    {
        float* x0f = &x0l[0][0];
        float* xf  = &xl[0][0];
        float* dxf = &dxl[0][0];
        for (int i = tid; i < NPART*3; i += 512) {
            float v = xs[b*(NPART*3) + i];
            x0f[i] = v; xf[i] = v; dxf[i] = 0.f;
        }
    }
    for (int idx = tid; idx < NPART*HID; idx += 512) {
        int n = idx >> 6, j = idx & 63;
        float acc = emb_b[j] + tb * emb_w[8*HID + j];
        #pragma unroll
        for (int k = 0; k < 8; ++k) acc += h_init[n*8 + k] * emb_w[k*HID + j];
        hsh[n][j] = acc;
        aggs[n][j] = 0.f;
    }
    for (int e = tid; e < 464; e += 512) {
        int ee = (e < NEDGE) ? e : 0;
        int a = ee / NDEG, r = ee - a*NDEG;
        int bb = r + (r >= a ? 1 : 0);
        srcT[e] = (unsigned char)a;
        dstT[e] = (unsigned char)bb;
    }
    __syncthreads();

    for (int L = 0; L < NLAYERS; ++L) {
        // ===== phase 1: stage edge weights bf16; vectors; Hr/Hc GEMV (global W) =====
        stage_wt(edge_w2  + L*HID*HID, wbuf,        tid);
        stage_wt(coord_w1 + L*HID*HID, wbuf + 8192, tid);
        if (tid < HID) {
            const float* w1 = edge_w1 + L*130*HID;
            vrad[tid] = w1[128*HID + tid];
            vea [tid] = w1[129*HID + tid];
            vb2 [tid] = edge_b2[L*HID + tid];
            vcb1[tid] = coord_b1[L*HID + tid];
            vcw2[tid] = coord_w2[L*HID + tid];
            vbn1[tid] = node_b1[L*HID + tid];
            vbn2[tid] = node_b2[L*HID + tid];
        }
        {
            const float* w1 = edge_w1 + L*130*HID;
            const int j  = tid & 63;
            const int nb = tid >> 6;   // 0..7
            float accr[3], accc[3];
            int ns[3];
            const float b1v = edge_b1[L*HID + j];
            #pragma unroll
            for (int m = 0; m < 3; ++m) {
                accr[m] = b1v; accc[m] = 0.f;
                int n = nb + 8*m;
                ns[m] = (n < NPART) ? n : 0;
            }
            #pragma unroll 4
            for (int k = 0; k < HID; ++k) {
                float wr = w1[k*HID + j];
                float wc = w1[(HID + k)*HID + j];
                #pragma unroll
                for (int m = 0; m < 3; ++m) {
                    float hv = hsh[ns[m]][k];
                    accr[m] += hv * wr;
                    accc[m] += hv * wc;
                }
            }
            #pragma unroll
            for (int m = 0; m < 3; ++m) {
                int n = nb + 8*m;
                if (n < NPART) { Hr[n][j] = accr[m]; Hc[n][j] = accc[m]; }
            }
        }
        __syncthreads();

        // ===== phase 2: edge strips, per-wave, no barriers =====
        {
            bf16x8 BW[2][4][2];
            #pragma unroll
            for (int g = 0; g < 2; ++g)
                #pragma unroll
                for (int nt = 0; nt < 4; ++nt) {
                    int j = nt*16 + j0;
                    const char* rp = wbuf + g*8192 + j*128;
                    int sw = (j & 7) << 4;
                    #pragma unroll
                    for (int c = 0; c < 2; ++c)
                        BW[g][nt][c] = *(const bf16x8*)(rp + ((c*64 + kg*16) ^ sw));
                }

            for (int s = w; s < NSTRIP; s += 8) {
                const int e0 = s * 16;
                const int ecnt = (NEDGE - e0 < 16) ? (NEDGE - e0) : 16;
                int eg = e0 + j0; if (eg >= NEDGE) eg = NEDGE - 1;
                const int a  = srcT[eg];
                const int bb = dstT[eg];
                float d0 = xl[a][0] - xl[bb][0];
                float d1 = xl[a][1] - xl[bb][1];
                float d2 = xl[a][2] - xl[bb][2];
                float rad = d0*d0 + d1*d1 + d2*d2;
                float inv = rsqrtf(rad + 1e-8f);
                float f0 = d0*inv, f1 = d1*inv, f2 = d2*inv;
                float g0 = x0l[a][0] - x0l[bb][0];
                float g1 = x0l[a][1] - x0l[bb][1];
                float g2 = x0l[a][2] - x0l[bb][2];
                float eav = g0*g0 + g1*g1 + g2*g2;
                if (l < 16) scal_sw[w][l] = 0.f;

                // m1 A-fragments in registers
                bf16x8 Ah[2], Al[2];
                {
                    const float* hrp = &Hr[a][0];
                    const float* hcp = &Hc[bb][0];
                    #pragma unroll
                    for (int c = 0; c < 2; ++c) {
                        const int k0 = c*32 + kg*8;
                        float tv[8];
                        #pragma unroll
                        for (int i = 0; i < 8; ++i) {
                            int k = k0 + i;
                            tv[i] = silu_f(hrp[k] + hcp[k] + rad*vrad[k] + eav*vea[k]);
                        }
                        split8(tv, Ah[c], Al[c]);
                    }
                }
                // GEMM1: m = m1 @ W2
                f32x4 acc[4];
                #pragma unroll
                for (int nt = 0; nt < 4; ++nt) {
                    f32x4 z = {0.f, 0.f, 0.f, 0.f};
                    z = __builtin_amdgcn_mfma_f32_16x16x32_bf16(Ah[0], BW[0][nt][0], z, 0, 0, 0);
                    z = __builtin_amdgcn_mfma_f32_16x16x32_bf16(Al[0], BW[0][nt][0], z, 0, 0, 0);
                    z = __builtin_amdgcn_mfma_f32_16x16x32_bf16(Ah[1], BW[0][nt][1], z, 0, 0, 0);
                    z = __builtin_amdgcn_mfma_f32_16x16x32_bf16(Al[1], BW[0][nt][1], z, 0, 0, 0);
                    acc[nt] = z;
                }
                // epilogue 1: silu+bias, pack to wave tile, agg atomics
                int ab[4], emask[4];
                #pragma unroll
                for (int r = 0; r < 4; ++r) {
                    int e2 = kg*4 + r;
                    int eg2 = e0 + e2; if (eg2 >= NEDGE) eg2 = NEDGE - 1;
                    ab[r] = (int)srcT[eg2] * NS;
                    emask[r] = (e2 < ecnt);
                }
                #pragma unroll
                for (int nt = 0; nt < 4; ++nt) {
                    int j = nt*16 + j0;
                    float bv = vb2[j];
                    #pragma unroll
                    for (int r = 0; r < 4; ++r) {
                        float mv = silu_f(acc[nt][r] + bv);
                        mw[(kg*4 + r)*MWS + j] = pack_hl(mv);
                        if (emask[r]) atomicAdd(&aggsF[ab[r] + j], mv);
                    }
                }
                // GEMM2 A-fragments from packed wave tile
                bf16x8 A2h[2], A2l[2];
                {
                    const unsigned* arp = mw + j0*MWS;
                    #pragma unroll
                    for (int c = 0; c < 2; ++c) {
                        const int k0 = c*32 + kg*8;
                        u32x4 qa = *(const u32x4*)(arp + k0);
                        u32x4 qb = *(const u32x4*)(arp + k0 + 4);
                        u32x4 hw, lw;
                        hw[0] = (qa[0] & 0xffffu) | (qa[1] << 16);
                        hw[1] = (qa[2] & 0xffffu) | (qa[3] << 16);
                        hw[2] = (qb[0] & 0xffffu) | (qb[1] << 16);
                        hw[3] = (qb[2] & 0xffffu) | (qb[3] << 16);
                        lw[0] = (qa[0] >> 16) | (qa[1] & 0xffff0000u);
                        lw[1] = (qa[2] >> 16) | (qa[3] & 0xffff0000u);
                        lw[2] = (qb[0] >> 16) | (qb[1] & 0xffff0000u);
                        lw[3] = (qb[2] >> 16) | (qb[3] & 0xffff0000u);
                        A2h[c] = __builtin_bit_cast(bf16x8, hw);
                        A2l[c] = __builtin_bit_cast(bf16x8, lw);
                    }
                }
                // GEMM2: c1 = m @ Wc1
                f32x4 acc2[4];
                #pragma unroll
                for (int nt = 0; nt < 4; ++nt) {
                    f32x4 z = {0.f, 0.f, 0.f, 0.f};
                    z = __builtin_amdgcn_mfma_f32_16x16x32_bf16(A2h[0], BW[1][nt][0], z, 0, 0, 0);
                    z = __builtin_amdgcn_mfma_f32_16x16x32_bf16(A2l[0], BW[1][nt][0], z, 0, 0, 0);
                    z = __builtin_amdgcn_mfma_f32_16x16x32_bf16(A2h[1], BW[1][nt][1], z, 0, 0, 0);
                    z = __builtin_amdgcn_mfma_f32_16x16x32_bf16(A2l[1], BW[1][nt][1], z, 0, 0, 0);
                    acc2[nt] = z;
                }
                // epilogue 2: scal partials -> wave LDS atomics
                float pr[4] = {0.f, 0.f, 0.f, 0.f};
                #pragma unroll
                for (int nt = 0; nt < 4; ++nt) {
                    int j = nt*16 + j0;
                    float cb = vcb1[j], cw = vcw2[j];
                    #pragma unroll
                    for (int r = 0; r < 4; ++r)
                        pr[r] += silu_f(acc2[nt][r] + cb) * cw;
                }
                #pragma unroll
                for (int r = 0; r < 4; ++r)
                    atomicAdd(&scal_sw[w][kg*4 + r], pr[r]);
                if (l < 16 && l < ecnt) {
                    float sc = scal_sw[w][l];
                    atomicAdd(&dxl[a][0], f0 * sc);
                    atomicAdd(&dxl[a][1], f1 * sc);
                    atomicAdd(&dxl[a][2], f2 * sc);
                }
            }
        }
        __syncthreads();

        // ===== x update =====
        if (tid < NPART*3) {
            int n = tid / 3, d = tid - n*3;
            xl[n][d] += dxl[n][d];
            dxl[n][d] = 0.f;
        }
        if (L < NLAYERS - 1) {
            // node MLP with weights straight from global (L2-hot)
            const float* wn1 = node_w1 + L*2*HID*HID;
            const int j  = tid & 63;
            const int nb = tid >> 6;
            float acc[3]; int ns[3];
            #pragma unroll
            for (int m = 0; m < 3; ++m) {
                int n = nb + 8*m;
                ns[m] = (n < NPART) ? n : 0;
                acc[m] = vbn1[j];
            }
            #pragma unroll 4
            for (int k = 0; k < HID; ++k) {
                float w1v = wn1[k*64 + j];
                float w2v = wn1[(64 + k)*64 + j];
                #pragma unroll
                for (int m = 0; m < 3; ++m)
                    acc[m] += hsh[ns[m]][k]*w1v + aggs[ns[m]][k]*w2v;
            }
            __syncthreads();   // hn overwrites Hr: ensure edge phase fully done (it is) & ordering
            #pragma unroll
            for (int m = 0; m < 3; ++m) {
                int n = nb + 8*m;
                if (n < NPART) Hr[n][j] = silu_f(acc[m]);
            }
            __syncthreads();
            const float* wn2 = node_w2 + L*HID*HID;
            float acc2[3];
            #pragma unroll
            for (int m = 0; m < 3; ++m) acc2[m] = vbn2[j];
            #pragma unroll 4
            for (int k = 0; k < HID; ++k) {
                float wv = wn2[k*64 + j];
                #pragma unroll
                for (int m = 0; m < 3; ++m) acc2[m] += Hr[ns[m]][k]*wv;
            }
            #pragma unroll
            for (int m = 0; m < 3; ++m) {
                int n = nb + 8*m;
                if (n < NPART) { hsh[n][j] += acc2[m]; aggs[n][j] = 0.f; }
            }
            __syncthreads();
        } else {
            __syncthreads();
        }
    }

    // ---- vel = (x - x0) - mean ----
    if (tid < 3) {
        float s = 0.f;
        #pragma unroll
        for (int n = 0; n < NPART; ++n) s += xl[n][tid] - x0l[n][tid];
        meanv[tid] = s / (float)NPART;
    }
    __syncthreads();
    if (tid < NPART*3) {
        int n = tid / 3, d = tid - n*3;
        out[b*(NPART*3) + tid] = (xl[n][d] - x0l[n][d]) - meanv[d];
    }
}

extern "C" void kernel_launch(void* const* d_in, const int* in_sizes, int n_in,
                              void* d_out, int out_size, void* d_ws, size_t ws_size,
                              hipStream_t stream) {
    const float* t_in     = (const float*)d_in[0];
    const float* xs       = (const float*)d_in[1];
    const float* h_init   = (const float*)d_in[2];
    const float* emb_w    = (const float*)d_in[3];
    const float* emb_b    = (const float*)d_in[4];
    const float* edge_w1  = (const float*)d_in[7];
    const float* edge_b1  = (const float*)d_in[8];
    const float* edge_w2  = (const float*)d_in[9];
    const float* edge_b2  = (const float*)d_in[10];
    const float* node_w1  = (const float*)d_in[11];
    const float* node_b1  = (const float*)d_in[12];
    const float* node_w2  = (const float*)d_in[13];
    const float* node_b2  = (const float*)d_in[14];
    const float* coord_w1 = (const float*)d_in[15];
    const float* coord_b1 = (const float*)d_in[16];
    const float* coord_w2 = (const float*)d_in[17];
    float* outp = (float*)d_out;

    const int Bn = in_sizes[0];
    egnn_fused<<<Bn, 512, 0, stream>>>(
        t_in, xs, h_init, emb_w, emb_b,
        edge_w1, edge_b1, edge_w2, edge_b2,
        node_w1, node_b1, node_w2, node_b2,
        coord_w1, coord_b1, coord_w2, outp);
}

// Round 5
// 1076.521 us; speedup vs baseline: 1.0252x; 1.0252x over previous
//
#include <hip/hip_runtime.h>
#include <hip/hip_bf16.h>

#define NPART 22
#define NDEG  21
#define NEDGE 462
#define HID   64
#define NLAYERS 4
#define NSTRIP 29
#define NS    68     // padded row stride (floats) for node-indexed arrays
#define MWS   68     // u32 row stride of wave-private m tile

typedef __attribute__((ext_vector_type(8))) short bf16x8;
typedef __attribute__((ext_vector_type(4))) float f32x4;
typedef __attribute__((ext_vector_type(4))) unsigned int u32x4;

__device__ __forceinline__ float silu_f(float v) {
    return __fdividef(v, 1.0f + __expf(-v));
}
__device__ __forceinline__ unsigned short bfu(float v) {
    return __bfloat16_as_ushort(__float2bfloat16(v));
}
__device__ __forceinline__ float bf2f(unsigned h) { return __uint_as_float(h << 16); }

// pack f32 -> (hi bf16) | (lo bf16 << 16)
__device__ __forceinline__ unsigned pack_hl(float v) {
    unsigned short h = bfu(v);
    float r = v - bf2f(h);
    return (unsigned)h | ((unsigned)bfu(r) << 16);
}

// split 8 f32 into hi/lo bf16x8 fragments
__device__ __forceinline__ void split8(const float* va, bf16x8& hi, bf16x8& lo) {
    #pragma unroll
    for (int i = 0; i < 8; ++i) {
        unsigned short h = bfu(va[i]);
        hi[i] = (short)h;
        lo[i] = (short)bfu(va[i] - bf2f(h));
    }
}

// Stage 64x64 f32 row-major [k][j] -> LDS transposed single bf16 [j][k],
// row 128 B, swizzle: byte_k ^ ((j&7)<<4).  512 threads.
__device__ __forceinline__ void stage_wt(const float* __restrict__ Wg,
                                         char* dst, int tid) {
    const int j  = tid & 63;
    const int kb = tid >> 6;     // 0..7 -> 8 k each
    u32x4 p;
    #pragma unroll
    for (int i = 0; i < 8; i += 2) {
        float v0 = Wg[(kb*8 + i) * 64 + j];
        float v1 = Wg[(kb*8 + i + 1) * 64 + j];
        p[i >> 1] = (unsigned)bfu(v0) | ((unsigned)bfu(v1) << 16);
    }
    *(u32x4*)(dst + j * 128 + ((kb*16) ^ ((j & 7) << 4))) = p;
}

__global__ __launch_bounds__(512, 2)
void egnn_fused(const float* __restrict__ t_in,
                const float* __restrict__ xs,
                const float* __restrict__ h_init,
                const float* __restrict__ emb_w,
                const float* __restrict__ emb_b,
                const float* __restrict__ edge_w1,
                const float* __restrict__ edge_b1,
                const float* __restrict__ edge_w2,
                const float* __restrict__ edge_b2,
                const float* __restrict__ node_w1,
                const float* __restrict__ node_b1,
                const float* __restrict__ node_w2,
                const float* __restrict__ node_b2,
                const float* __restrict__ coord_w1,
                const float* __restrict__ coord_b1,
                const float* __restrict__ coord_w2,
                float* __restrict__ out)
{
    __shared__ __align__(16) char     wbuf[16384];          // W2t bf16 | Wc1t bf16
    __shared__ __align__(16) unsigned mwav[8 * 16 * MWS];   // packed hi/lo m tiles
    __shared__ __align__(16) float hsh [NPART][NS];
    __shared__ __align__(16) float Hr  [NPART][NS];         // also hn scratch
    __shared__ __align__(16) float Hc  [NPART][NS];
    __shared__ __align__(16) float aggs[NPART][NS];
    __shared__ float vrad[HID], vea[HID], vb2[HID];
    __shared__ float vcb1[HID], vcw2[HID], vbn1[HID], vbn2[HID];
    __shared__ float xl[NPART][3], x0l[NPART][3], dxl[NPART][3];
    __shared__ float scal_sw[8][16];
    __shared__ unsigned char srcT[464], dstT[464];
    __shared__ float meanv[3];

    const int b   = blockIdx.x;
    const int tid = threadIdx.x;
    const int l   = tid & 63;
    const int w   = tid >> 6;          // 0..7
    const int kg  = l >> 4;
    const int j0  = l & 15;
    const float tb = t_in[b];
    float* aggsF = &aggs[0][0];
    unsigned* mw = mwav + w * 16 * MWS;

    // ---- init ----
    {
        float* x0f = &x0l[0][0];
        float* xf  = &xl[0][0];
        float* dxf = &dxl[0][0];
        for (int i = tid; i < NPART*3; i += 512) {
            float v = xs[b*(NPART*3) + i];
            x0f[i] = v; xf[i] = v; dxf[i] = 0.f;
        }
    }
    for (int idx = tid; idx < NPART*HID; idx += 512) {
        int n = idx >> 6, j = idx & 63;
        float acc = emb_b[j] + tb * emb_w[8*HID + j];
        #pragma unroll
        for (int k = 0; k < 8; ++k) acc += h_init[n*8 + k] * emb_w[k*HID + j];
        hsh[n][j] = acc;
        aggs[n][j] = 0.f;
    }
    for (int e = tid; e < 464; e += 512) {
        int ee = (e < NEDGE) ? e : 0;
        int a = ee / NDEG, r = ee - a*NDEG;
        int bb = r + (r >= a ? 1 : 0);
        srcT[e] = (unsigned char)a;
        dstT[e] = (unsigned char)bb;
    }
    __syncthreads();

    for (int L = 0; L < NLAYERS; ++L) {
        // ===== phase 1: stage edge weights bf16; vectors; Hr/Hc GEMV (global W) =====
        stage_wt(edge_w2  + L*HID*HID, wbuf,        tid);
        stage_wt(coord_w1 + L*HID*HID, wbuf + 8192, tid);
        if (tid < HID) {
            const float* w1 = edge_w1 + L*130*HID;
            vrad[tid] = w1[128*HID + tid];
            vea [tid] = w1[129*HID + tid];
            vb2 [tid] = edge_b2[L*HID + tid];
            vcb1[tid] = coord_b1[L*HID + tid];
            vcw2[tid] = coord_w2[L*HID + tid];
            vbn1[tid] = node_b1[L*HID + tid];
            vbn2[tid] = node_b2[L*HID + tid];
        }
        {
            const float* w1 = edge_w1 + L*130*HID;
            const int j  = tid & 63;
            const int nb = tid >> 6;   // 0..7
            float accr[3], accc[3];
            int ns[3];
            const float b1v = edge_b1[L*HID + j];
            #pragma unroll
            for (int m = 0; m < 3; ++m) {
                accr[m] = b1v; accc[m] = 0.f;
                int n = nb + 8*m;
                ns[m] = (n < NPART) ? n : 0;
            }
            #pragma unroll 4
            for (int k = 0; k < HID; ++k) {
                float wr = w1[k*HID + j];
                float wc = w1[(HID + k)*HID + j];
                #pragma unroll
                for (int m = 0; m < 3; ++m) {
                    float hv = hsh[ns[m]][k];
                    accr[m] += hv * wr;
                    accc[m] += hv * wc;
                }
            }
            #pragma unroll
            for (int m = 0; m < 3; ++m) {
                int n = nb + 8*m;
                if (n < NPART) { Hr[n][j] = accr[m]; Hc[n][j] = accc[m]; }
            }
        }
        __syncthreads();

        // ===== phase 2: edge strips, per-wave, no barriers =====
        {
            // hoist only GEMM1 B-fragments (32 VGPRs); GEMM2's read per strip
            bf16x8 BW1[4][2];
            #pragma unroll
            for (int nt = 0; nt < 4; ++nt) {
                int j = nt*16 + j0;
                const char* rp = wbuf + j*128;
                int sw = (j & 7) << 4;
                #pragma unroll
                for (int c = 0; c < 2; ++c)
                    BW1[nt][c] = *(const bf16x8*)(rp + ((c*64 + kg*16) ^ sw));
            }

            for (int s = w; s < NSTRIP; s += 8) {
                const int e0 = s * 16;
                const int ecnt = (NEDGE - e0 < 16) ? (NEDGE - e0) : 16;
                int eg = e0 + j0; if (eg >= NEDGE) eg = NEDGE - 1;
                const int a  = srcT[eg];
                const int bb = dstT[eg];
                float d0 = xl[a][0] - xl[bb][0];
                float d1 = xl[a][1] - xl[bb][1];
                float d2 = xl[a][2] - xl[bb][2];
                float rad = d0*d0 + d1*d1 + d2*d2;
                float inv = rsqrtf(rad + 1e-8f);
                float f0 = d0*inv, f1 = d1*inv, f2 = d2*inv;
                float g0 = x0l[a][0] - x0l[bb][0];
                float g1 = x0l[a][1] - x0l[bb][1];
                float g2 = x0l[a][2] - x0l[bb][2];
                float eav = g0*g0 + g1*g1 + g2*g2;
                if (l < 16) scal_sw[w][l] = 0.f;

                // m1 A-fragments in registers
                bf16x8 Ah[2], Al[2];
                {
                    const float* hrp = &Hr[a][0];
                    const float* hcp = &Hc[bb][0];
                    #pragma unroll
                    for (int c = 0; c < 2; ++c) {
                        const int k0 = c*32 + kg*8;
                        float tv[8];
                        #pragma unroll
                        for (int i = 0; i < 8; ++i) {
                            int k = k0 + i;
                            tv[i] = silu_f(hrp[k] + hcp[k] + rad*vrad[k] + eav*vea[k]);
                        }
                        split8(tv, Ah[c], Al[c]);
                    }
                }
                // GEMM1: m = m1 @ W2
                f32x4 acc[4];
                #pragma unroll
                for (int nt = 0; nt < 4; ++nt) {
                    f32x4 z = {0.f, 0.f, 0.f, 0.f};
                    z = __builtin_amdgcn_mfma_f32_16x16x32_bf16(Ah[0], BW1[nt][0], z, 0, 0, 0);
                    z = __builtin_amdgcn_mfma_f32_16x16x32_bf16(Al[0], BW1[nt][0], z, 0, 0, 0);
                    z = __builtin_amdgcn_mfma_f32_16x16x32_bf16(Ah[1], BW1[nt][1], z, 0, 0, 0);
                    z = __builtin_amdgcn_mfma_f32_16x16x32_bf16(Al[1], BW1[nt][1], z, 0, 0, 0);
                    acc[nt] = z;
                }
                // issue GEMM2 B-fragment loads now; latency hides under epilogue 1
                bf16x8 B2[4][2];
                #pragma unroll
                for (int nt = 0; nt < 4; ++nt) {
                    int j = nt*16 + j0;
                    const char* rp = wbuf + 8192 + j*128;
                    int sw = (j & 7) << 4;
                    #pragma unroll
                    for (int c = 0; c < 2; ++c)
                        B2[nt][c] = *(const bf16x8*)(rp + ((c*64 + kg*16) ^ sw));
                }
                // epilogue 1: silu+bias, pack to wave tile, agg atomics
                int ab[4], emask[4];
                #pragma unroll
                for (int r = 0; r < 4; ++r) {
                    int e2 = kg*4 + r;
                    int eg2 = e0 + e2; if (eg2 >= NEDGE) eg2 = NEDGE - 1;
                    ab[r] = (int)srcT[eg2] * NS;
                    emask[r] = (e2 < ecnt);
                }
                #pragma unroll
                for (int nt = 0; nt < 4; ++nt) {
                    int j = nt*16 + j0;
                    float bv = vb2[j];
                    #pragma unroll
                    for (int r = 0; r < 4; ++r) {
                        float mv = silu_f(acc[nt][r] + bv);
                        mw[(kg*4 + r)*MWS + j] = pack_hl(mv);
                        if (emask[r]) atomicAdd(&aggsF[ab[r] + j], mv);
                    }
                }
                // GEMM2 A-fragments from packed wave tile
                bf16x8 A2h[2], A2l[2];
                {
                    const unsigned* arp = mw + j0*MWS;
                    #pragma unroll
                    for (int c = 0; c < 2; ++c) {
                        const int k0 = c*32 + kg*8;
                        u32x4 qa = *(const u32x4*)(arp + k0);
                        u32x4 qb = *(const u32x4*)(arp + k0 + 4);
                        u32x4 hw, lw;
                        hw[0] = (qa[0] & 0xffffu) | (qa[1] << 16);
                        hw[1] = (qa[2] & 0xffffu) | (qa[3] << 16);
                        hw[2] = (qb[0] & 0xffffu) | (qb[1] << 16);
                        hw[3] = (qb[2] & 0xffffu) | (qb[3] << 16);
                        lw[0] = (qa[0] >> 16) | (qa[1] & 0xffff0000u);
                        lw[1] = (qa[2] >> 16) | (qa[3] & 0xffff0000u);
                        lw[2] = (qb[0] >> 16) | (qb[1] & 0xffff0000u);
                        lw[3] = (qb[2] >> 16) | (qb[3] & 0xffff0000u);
                        A2h[c] = __builtin_bit_cast(bf16x8, hw);
                        A2l[c] = __builtin_bit_cast(bf16x8, lw);
                    }
                }
                // GEMM2: c1 = m @ Wc1
                f32x4 acc2[4];
                #pragma unroll
                for (int nt = 0; nt < 4; ++nt) {
                    f32x4 z = {0.f, 0.f, 0.f, 0.f};
                    z = __builtin_amdgcn_mfma_f32_16x16x32_bf16(A2h[0], B2[nt][0], z, 0, 0, 0);
                    z = __builtin_amdgcn_mfma_f32_16x16x32_bf16(A2l[0], B2[nt][0], z, 0, 0, 0);
                    z = __builtin_amdgcn_mfma_f32_16x16x32_bf16(A2h[1], B2[nt][1], z, 0, 0, 0);
                    z = __builtin_amdgcn_mfma_f32_16x16x32_bf16(A2l[1], B2[nt][1], z, 0, 0, 0);
                    acc2[nt] = z;
                }
                // epilogue 2: scal partials -> wave LDS atomics
                float pr[4] = {0.f, 0.f, 0.f, 0.f};
                #pragma unroll
                for (int nt = 0; nt < 4; ++nt) {
                    int j = nt*16 + j0;
                    float cb = vcb1[j], cw = vcw2[j];
                    #pragma unroll
                    for (int r = 0; r < 4; ++r)
                        pr[r] += silu_f(acc2[nt][r] + cb) * cw;
                }
                #pragma unroll
                for (int r = 0; r < 4; ++r)
                    atomicAdd(&scal_sw[w][kg*4 + r], pr[r]);
                if (l < 16 && l < ecnt) {
                    float sc = scal_sw[w][l];
                    atomicAdd(&dxl[a][0], f0 * sc);
                    atomicAdd(&dxl[a][1], f1 * sc);
                    atomicAdd(&dxl[a][2], f2 * sc);
                }
            }
        }
        __syncthreads();

        // ===== x update =====
        if (tid < NPART*3) {
            int n = tid / 3, d = tid - n*3;
            xl[n][d] += dxl[n][d];
            dxl[n][d] = 0.f;
        }
        if (L < NLAYERS - 1) {
            // node MLP with weights straight from global (L2-hot)
            const float* wn1 = node_w1 + L*2*HID*HID;
            const int j  = tid & 63;
            const int nb = tid >> 6;
            float acc[3]; int ns[3];
            #pragma unroll
            for (int m = 0; m < 3; ++m) {
                int n = nb + 8*m;
                ns[m] = (n < NPART) ? n : 0;
                acc[m] = vbn1[j];
            }
            #pragma unroll 4
            for (int k = 0; k < HID; ++k) {
                float w1v = wn1[k*64 + j];
                float w2v = wn1[(64 + k)*64 + j];
                #pragma unroll
                for (int m = 0; m < 3; ++m)
                    acc[m] += hsh[ns[m]][k]*w1v + aggs[ns[m]][k]*w2v;
            }
            __syncthreads();
            #pragma unroll
            for (int m = 0; m < 3; ++m) {
                int n = nb + 8*m;
                if (n < NPART) Hr[n][j] = silu_f(acc[m]);
            }
            __syncthreads();
            const float* wn2 = node_w2 + L*HID*HID;
            float acc2[3];
            #pragma unroll
            for (int m = 0; m < 3; ++m) acc2[m] = vbn2[j];
            #pragma unroll 4
            for (int k = 0; k < HID; ++k) {
                float wv = wn2[k*64 + j];
                #pragma unroll
                for (int m = 0; m < 3; ++m) acc2[m] += Hr[ns[m]][k]*wv;
            }
            #pragma unroll
            for (int m = 0; m < 3; ++m) {
                int n = nb + 8*m;
                if (n < NPART) { hsh[n][j] += acc2[m]; aggs[n][j] = 0.f; }
            }
            __syncthreads();
        } else {
            __syncthreads();
        }
    }

    // ---- vel = (x - x0) - mean ----
    if (tid < 3) {
        float s = 0.f;
        #pragma unroll
        for (int n = 0; n < NPART; ++n) s += xl[n][tid] - x0l[n][tid];
        meanv[tid] = s / (float)NPART;
    }
    __syncthreads();
    if (tid < NPART*3) {
        int n = tid / 3, d = tid - n*3;
        out[b*(NPART*3) + tid] = (xl[n][d] - x0l[n][d]) - meanv[d];
    }
}

extern "C" void kernel_launch(void* const* d_in, const int* in_sizes, int n_in,
                              void* d_out, int out_size, void* d_ws, size_t ws_size,
                              hipStream_t stream) {
    const float* t_in     = (const float*)d_in[0];
    const float* xs       = (const float*)d_in[1];
    const float* h_init   = (const float*)d_in[2];
    const float* emb_w    = (const float*)d_in[3];
    const float* emb_b    = (const float*)d_in[4];
    const float* edge_w1  = (const float*)d_in[7];
    const float* edge_b1  = (const float*)d_in[8];
    const float* edge_w2  = (const float*)d_in[9];
    const float* edge_b2  = (const float*)d_in[10];
    const float* node_w1  = (const float*)d_in[11];
    const float* node_b1  = (const float*)d_in[12];
    const float* node_w2  = (const float*)d_in[13];
    const float* node_b2  = (const float*)d_in[14];
    const float* coord_w1 = (const float*)d_in[15];
    const float* coord_b1 = (const float*)d_in[16];
    const float* coord_w2 = (const float*)d_in[17];
    float* outp = (float*)d_out;

    const int Bn = in_sizes[0];
    egnn_fused<<<Bn, 512, 0, stream>>>(
        t_in, xs, h_init, emb_w, emb_b,
        edge_w1, edge_b1, edge_w2, edge_b2,
        node_w1, node_b1, node_w2, node_b2,
        coord_w1, coord_b1, coord_w2, outp);
}

// Round 6
// 1007.811 us; speedup vs baseline: 1.0951x; 1.0682x over previous
//
#include <hip/hip_runtime.h>
#include <hip/hip_bf16.h>

#define NPART 22
#define NDEG  21
#define NEDGE 462
#define HID   64
#define NLAYERS 4
#define NSTRIP 29
#define NS    68     // padded row stride (floats) for node-indexed arrays
#define MWS   68     // u32 row stride of wave-private m tile (16B-aligned rows)

typedef __attribute__((ext_vector_type(8))) short bf16x8;
typedef __attribute__((ext_vector_type(4))) float f32x4;
typedef __attribute__((ext_vector_type(4))) unsigned int u32x4;

__device__ __forceinline__ float silu_f(float v) {
    return __fdividef(v, 1.0f + __expf(-v));
}
__device__ __forceinline__ unsigned short bfu(float v) {
    return __bfloat16_as_ushort(__float2bfloat16(v));
}
__device__ __forceinline__ float bf2f(unsigned h) { return __uint_as_float(h << 16); }

// pack f32 -> (hi bf16) | (lo bf16 << 16)
__device__ __forceinline__ unsigned pack_hl(float v) {
    unsigned short h = bfu(v);
    float r = v - bf2f(h);
    return (unsigned)h | ((unsigned)bfu(r) << 16);
}

// split 8 f32 into hi/lo bf16x8 fragments
__device__ __forceinline__ void split8(const float* va, bf16x8& hi, bf16x8& lo) {
    #pragma unroll
    for (int i = 0; i < 8; ++i) {
        unsigned short h = bfu(va[i]);
        hi[i] = (short)h;
        lo[i] = (short)bfu(va[i] - bf2f(h));
    }
}

// Precompute MFMA B-fragments (bf16, transposed) of edge_w2 / coord_w1 for
// all 4 layers into ws. Layout: mat = L*2 + {0:W2, 1:Wc1};
// frag (nt,c) of mat m at u32x4 index m*512 + (nt*2+c)*64 + lane.
__global__ void prep_wfrag(const float* __restrict__ edge_w2,
                           const float* __restrict__ coord_w1,
                           unsigned* __restrict__ ws)
{
    const int m = blockIdx.x;      // 0..7
    const int l = threadIdx.x;     // 0..63
    const int L = m >> 1;
    const float* W = (m & 1) ? (coord_w1 + L*HID*HID) : (edge_w2 + L*HID*HID);
    const int kg = l >> 4, j0 = l & 15;
    u32x4* ws4 = (u32x4*)ws;
    #pragma unroll
    for (int nt = 0; nt < 4; ++nt) {
        #pragma unroll
        for (int c = 0; c < 2; ++c) {
            u32x4 p;
            #pragma unroll
            for (int pi = 0; pi < 4; ++pi) {
                int k = c*32 + kg*8 + 2*pi;
                float v0 = W[k*HID + nt*16 + j0];
                float v1 = W[(k+1)*HID + nt*16 + j0];
                p[pi] = (unsigned)bfu(v0) | ((unsigned)bfu(v1) << 16);
            }
            ws4[m*512 + (nt*2 + c)*64 + l] = p;
        }
    }
}

__global__ __launch_bounds__(256, 3)
void egnn_fused(const float* __restrict__ t_in,
                const float* __restrict__ xs,
                const float* __restrict__ h_init,
                const float* __restrict__ emb_w,
                const float* __restrict__ emb_b,
                const float* __restrict__ edge_w1,
                const float* __restrict__ edge_b1,
                const float* __restrict__ edge_b2,
                const float* __restrict__ node_w1,
                const float* __restrict__ node_b1,
                const float* __restrict__ node_w2,
                const float* __restrict__ node_b2,
                const float* __restrict__ coord_b1,
                const float* __restrict__ coord_w2,
                const unsigned* __restrict__ ws,
                float* __restrict__ out)
{
    __shared__ __align__(16) unsigned mwav[4 * 16 * MWS];   // packed hi/lo m tiles
    __shared__ __align__(16) float hsh [NPART][NS];
    __shared__ __align__(16) float Hr  [NPART][NS];         // also hn scratch
    __shared__ __align__(16) float Hc  [NPART][NS];
    __shared__ __align__(16) float aggs[NPART][NS];
    __shared__ float vrad[HID], vea[HID], vb2[HID];
    __shared__ float vcb1[HID], vcw2[HID], vbn1[HID], vbn2[HID];
    __shared__ float xl[NPART][3], x0l[NPART][3], dxl[NPART][3];
    __shared__ float scal_sw[4][16];
    __shared__ unsigned char srcT[464], dstT[464];
    __shared__ float meanv[3];

    const int b   = blockIdx.x;
    const int tid = threadIdx.x;
    const int l   = tid & 63;
    const int w   = tid >> 6;          // 0..3
    const int kg  = l >> 4;
    const int j0  = l & 15;
    const float tb = t_in[b];
    float* aggsF = &aggs[0][0];
    unsigned* mw = mwav + w * 16 * MWS;
    const u32x4* ws4 = (const u32x4*)ws;

    // ---- init ----
    {
        float* x0f = &x0l[0][0];
        float* xf  = &xl[0][0];
        float* dxf = &dxl[0][0];
        for (int i = tid; i < NPART*3; i += 256) {
            float v = xs[b*(NPART*3) + i];
            x0f[i] = v; xf[i] = v; dxf[i] = 0.f;
        }
    }
    for (int idx = tid; idx < NPART*HID; idx += 256) {
        int n = idx >> 6, j = idx & 63;
        float acc = emb_b[j] + tb * emb_w[8*HID + j];
        #pragma unroll
        for (int k = 0; k < 8; ++k) acc += h_init[n*8 + k] * emb_w[k*HID + j];
        hsh[n][j] = acc;
        aggs[n][j] = 0.f;
    }
    for (int e = tid; e < 464; e += 256) {
        int ee = (e < NEDGE) ? e : 0;
        int a = ee / NDEG, r = ee - a*NDEG;
        int bb = r + (r >= a ? 1 : 0);
        srcT[e] = (unsigned char)a;
        dstT[e] = (unsigned char)bb;
    }
    __syncthreads();

    for (int L = 0; L < NLAYERS; ++L) {
        // ===== phase 1: per-layer vectors; Hr/Hc GEMV (weights from global) =====
        if (tid < HID) {
            const float* w1 = edge_w1 + L*130*HID;
            vrad[tid] = w1[128*HID + tid];
            vea [tid] = w1[129*HID + tid];
            vb2 [tid] = edge_b2[L*HID + tid];
            vcb1[tid] = coord_b1[L*HID + tid];
            vcw2[tid] = coord_w2[L*HID + tid];
            vbn1[tid] = node_b1[L*HID + tid];
            vbn2[tid] = node_b2[L*HID + tid];
        }
        {
            const float* w1 = edge_w1 + L*130*HID;
            const int j  = tid & 63;
            const int nb = tid >> 6;   // 0..3
            float accr[6], accc[6];
            int ns[6];
            const float b1v = edge_b1[L*HID + j];
            #pragma unroll
            for (int m = 0; m < 6; ++m) {
                accr[m] = b1v; accc[m] = 0.f;
                int n = nb + 4*m;
                ns[m] = (n < NPART) ? n : 0;
            }
            #pragma unroll 4
            for (int k = 0; k < HID; ++k) {
                float wr = w1[k*HID + j];
                float wc = w1[(HID + k)*HID + j];
                #pragma unroll
                for (int m = 0; m < 6; ++m) {
                    float hv = hsh[ns[m]][k];
                    accr[m] += hv * wr;
                    accc[m] += hv * wc;
                }
            }
            #pragma unroll
            for (int m = 0; m < 6; ++m) {
                int n = nb + 4*m;
                if (n < NPART) { Hr[n][j] = accr[m]; Hc[n][j] = accc[m]; }
            }
        }
        __syncthreads();

        // ===== phase 2: edge strips, per-wave, no barriers =====
        {
            // B-fragments from ws (L2-hot, loop-invariant -> registers)
            bf16x8 BW1[4][2], B2[4][2];
            #pragma unroll
            for (int nt = 0; nt < 4; ++nt) {
                #pragma unroll
                for (int c = 0; c < 2; ++c) {
                    BW1[nt][c] = __builtin_bit_cast(bf16x8,
                        ws4[(L*2 + 0)*512 + (nt*2 + c)*64 + l]);
                    B2[nt][c]  = __builtin_bit_cast(bf16x8,
                        ws4[(L*2 + 1)*512 + (nt*2 + c)*64 + l]);
                }
            }

            for (int s = w; s < NSTRIP; s += 4) {
                const int e0 = s * 16;
                const int ecnt = (NEDGE - e0 < 16) ? (NEDGE - e0) : 16;
                int eg = e0 + j0; if (eg >= NEDGE) eg = NEDGE - 1;
                const int a  = srcT[eg];
                const int bb = dstT[eg];
                float d0 = xl[a][0] - xl[bb][0];
                float d1 = xl[a][1] - xl[bb][1];
                float d2 = xl[a][2] - xl[bb][2];
                float rad = d0*d0 + d1*d1 + d2*d2;
                float inv = rsqrtf(rad + 1e-8f);
                float f0 = d0*inv, f1 = d1*inv, f2 = d2*inv;
                float g0 = x0l[a][0] - x0l[bb][0];
                float g1 = x0l[a][1] - x0l[bb][1];
                float g2 = x0l[a][2] - x0l[bb][2];
                float eav = g0*g0 + g1*g1 + g2*g2;
                if (l < 16) scal_sw[w][l] = 0.f;

                // m1 A-fragments in registers
                bf16x8 Ah[2], Al[2];
                {
                    const float* hrp = &Hr[a][0];
                    const float* hcp = &Hc[bb][0];
                    #pragma unroll
                    for (int c = 0; c < 2; ++c) {
                        const int k0 = c*32 + kg*8;
                        float tv[8];
                        #pragma unroll
                        for (int i = 0; i < 8; ++i) {
                            int k = k0 + i;
                            tv[i] = silu_f(hrp[k] + hcp[k] + rad*vrad[k] + eav*vea[k]);
                        }
                        split8(tv, Ah[c], Al[c]);
                    }
                }
                // GEMM1: m = m1 @ W2
                f32x4 acc[4];
                #pragma unroll
                for (int nt = 0; nt < 4; ++nt) {
                    f32x4 z = {0.f, 0.f, 0.f, 0.f};
                    z = __builtin_amdgcn_mfma_f32_16x16x32_bf16(Ah[0], BW1[nt][0], z, 0, 0, 0);
                    z = __builtin_amdgcn_mfma_f32_16x16x32_bf16(Al[0], BW1[nt][0], z, 0, 0, 0);
                    z = __builtin_amdgcn_mfma_f32_16x16x32_bf16(Ah[1], BW1[nt][1], z, 0, 0, 0);
                    z = __builtin_amdgcn_mfma_f32_16x16x32_bf16(Al[1], BW1[nt][1], z, 0, 0, 0);
                    acc[nt] = z;
                }
                // epilogue 1: silu+bias, pack to wave tile, agg atomics
                int ab[4], emask[4];
                #pragma unroll
                for (int r = 0; r < 4; ++r) {
                    int e2 = kg*4 + r;
                    int eg2 = e0 + e2; if (eg2 >= NEDGE) eg2 = NEDGE - 1;
                    ab[r] = (int)srcT[eg2] * NS;
                    emask[r] = (e2 < ecnt);
                }
                #pragma unroll
                for (int nt = 0; nt < 4; ++nt) {
                    int j = nt*16 + j0;
                    float bv = vb2[j];
                    #pragma unroll
                    for (int r = 0; r < 4; ++r) {
                        float mv = silu_f(acc[nt][r] + bv);
                        mw[(kg*4 + r)*MWS + j] = pack_hl(mv);
                        if (emask[r]) atomicAdd(&aggsF[ab[r] + j], mv);
                    }
                }
                // GEMM2 A-fragments from packed wave tile
                bf16x8 A2h[2], A2l[2];
                {
                    const unsigned* arp = mw + j0*MWS;
                    #pragma unroll
                    for (int c = 0; c < 2; ++c) {
                        const int k0 = c*32 + kg*8;
                        u32x4 qa = *(const u32x4*)(arp + k0);
                        u32x4 qb = *(const u32x4*)(arp + k0 + 4);
                        u32x4 hw, lw;
                        hw[0] = (qa[0] & 0xffffu) | (qa[1] << 16);
                        hw[1] = (qa[2] & 0xffffu) | (qa[3] << 16);
                        hw[2] = (qb[0] & 0xffffu) | (qb[1] << 16);
                        hw[3] = (qb[2] & 0xffffu) | (qb[3] << 16);
                        lw[0] = (qa[0] >> 16) | (qa[1] & 0xffff0000u);
                        lw[1] = (qa[2] >> 16) | (qa[3] & 0xffff0000u);
                        lw[2] = (qb[0] >> 16) | (qb[1] & 0xffff0000u);
                        lw[3] = (qb[2] >> 16) | (qb[3] & 0xffff0000u);
                        A2h[c] = __builtin_bit_cast(bf16x8, hw);
                        A2l[c] = __builtin_bit_cast(bf16x8, lw);
                    }
                }
                // GEMM2: c1 = m @ Wc1
                f32x4 acc2[4];
                #pragma unroll
                for (int nt = 0; nt < 4; ++nt) {
                    f32x4 z = {0.f, 0.f, 0.f, 0.f};
                    z = __builtin_amdgcn_mfma_f32_16x16x32_bf16(A2h[0], B2[nt][0], z, 0, 0, 0);
                    z = __builtin_amdgcn_mfma_f32_16x16x32_bf16(A2l[0], B2[nt][0], z, 0, 0, 0);
                    z = __builtin_amdgcn_mfma_f32_16x16x32_bf16(A2h[1], B2[nt][1], z, 0, 0, 0);
                    z = __builtin_amdgcn_mfma_f32_16x16x32_bf16(A2l[1], B2[nt][1], z, 0, 0, 0);
                    acc2[nt] = z;
                }
                // epilogue 2: scal partials -> wave LDS atomics
                float pr[4] = {0.f, 0.f, 0.f, 0.f};
                #pragma unroll
                for (int nt = 0; nt < 4; ++nt) {
                    int j = nt*16 + j0;
                    float cb = vcb1[j], cw = vcw2[j];
                    #pragma unroll
                    for (int r = 0; r < 4; ++r)
                        pr[r] += silu_f(acc2[nt][r] + cb) * cw;
                }
                #pragma unroll
                for (int r = 0; r < 4; ++r)
                    atomicAdd(&scal_sw[w][kg*4 + r], pr[r]);
                if (l < 16 && l < ecnt) {
                    float sc = scal_sw[w][l];
                    atomicAdd(&dxl[a][0], f0 * sc);
                    atomicAdd(&dxl[a][1], f1 * sc);
                    atomicAdd(&dxl[a][2], f2 * sc);
                }
            }
        }
        __syncthreads();

        // ===== x update =====
        if (tid < NPART*3) {
            int n = tid / 3, d = tid - n*3;
            xl[n][d] += dxl[n][d];
            dxl[n][d] = 0.f;
        }
        if (L < NLAYERS - 1) {
            // node MLP with weights straight from global (L2-hot)
            const float* wn1 = node_w1 + L*2*HID*HID;
            const int j  = tid & 63;
            const int nb = tid >> 6;
            float acc[6]; int ns[6];
            #pragma unroll
            for (int m = 0; m < 6; ++m) {
                int n = nb + 4*m;
                ns[m] = (n < NPART) ? n : 0;
                acc[m] = vbn1[j];
            }
            #pragma unroll 4
            for (int k = 0; k < HID; ++k) {
                float w1v = wn1[k*64 + j];
                float w2v = wn1[(64 + k)*64 + j];
                #pragma unroll
                for (int m = 0; m < 6; ++m)
                    acc[m] += hsh[ns[m]][k]*w1v + aggs[ns[m]][k]*w2v;
            }
            __syncthreads();
            #pragma unroll
            for (int m = 0; m < 6; ++m) {
                int n = nb + 4*m;
                if (n < NPART) Hr[n][j] = silu_f(acc[m]);
            }
            __syncthreads();
            const float* wn2 = node_w2 + L*HID*HID;
            float acc2[6];
            #pragma unroll
            for (int m = 0; m < 6; ++m) acc2[m] = vbn2[j];
            #pragma unroll 4
            for (int k = 0; k < HID; ++k) {
                float wv = wn2[k*64 + j];
                #pragma unroll
                for (int m = 0; m < 6; ++m) acc2[m] += Hr[ns[m]][k]*wv;
            }
            #pragma unroll
            for (int m = 0; m < 6; ++m) {
                int n = nb + 4*m;
                if (n < NPART) { hsh[n][j] += acc2[m]; aggs[n][j] = 0.f; }
            }
            __syncthreads();
        } else {
            __syncthreads();
        }
    }

    // ---- vel = (x - x0) - mean ----
    if (tid < 3) {
        float s = 0.f;
        #pragma unroll
        for (int n = 0; n < NPART; ++n) s += xl[n][tid] - x0l[n][tid];
        meanv[tid] = s / (float)NPART;
    }
    __syncthreads();
    if (tid < NPART*3) {
        int n = tid / 3, d = tid - n*3;
        out[b*(NPART*3) + tid] = (xl[n][d] - x0l[n][d]) - meanv[d];
    }
}

extern "C" void kernel_launch(void* const* d_in, const int* in_sizes, int n_in,
                              void* d_out, int out_size, void* d_ws, size_t ws_size,
                              hipStream_t stream) {
    const float* t_in     = (const float*)d_in[0];
    const float* xs       = (const float*)d_in[1];
    const float* h_init   = (const float*)d_in[2];
    const float* emb_w    = (const float*)d_in[3];
    const float* emb_b    = (const float*)d_in[4];
    const float* edge_w1  = (const float*)d_in[7];
    const float* edge_b1  = (const float*)d_in[8];
    const float* edge_w2  = (const float*)d_in[9];
    const float* edge_b2  = (const float*)d_in[10];
    const float* node_w1  = (const float*)d_in[11];
    const float* node_b1  = (const float*)d_in[12];
    const float* node_w2  = (const float*)d_in[13];
    const float* node_b2  = (const float*)d_in[14];
    const float* coord_w1 = (const float*)d_in[15];
    const float* coord_b1 = (const float*)d_in[16];
    const float* coord_w2 = (const float*)d_in[17];
    float* outp  = (float*)d_out;
    unsigned* ws = (unsigned*)d_ws;

    const int Bn = in_sizes[0];
    prep_wfrag<<<8, 64, 0, stream>>>(edge_w2, coord_w1, ws);
    egnn_fused<<<Bn, 256, 0, stream>>>(
        t_in, xs, h_init, emb_w, emb_b,
        edge_w1, edge_b1, edge_b2,
        node_w1, node_b1, node_w2, node_b2,
        coord_b1, coord_w2, ws, outp);
}